// Round 9
// baseline (234.508 us; speedup 1.0000x reference)
//
#include <hip/hip_runtime.h>

typedef __attribute__((ext_vector_type(8))) short bf16x8;
typedef __attribute__((ext_vector_type(8))) _Float16 f16x8;
typedef __attribute__((ext_vector_type(2))) __fp16 fp16v2;
typedef __attribute__((ext_vector_type(16))) float f32x16;

#define DDIM 128
#define NADDR 4096
#define VDIM 512
#define MTOT 16384
#define NT 32
#define NTILES (NADDR/NT)      // 128 n-tiles
#define LOG2E 1.44269504088896340736f

// pack bf16-trunc(lo) into low short, bf16-trunc(hi) into high short
__device__ __forceinline__ unsigned pkhi(float hi, float lo){
  return __builtin_amdgcn_perm(__float_as_uint(hi), __float_as_uint(lo), 0x07060302u);
}

// ---------- prep 1: addr f32 [4096][128] -> K tiles f16, FRAG-MAJOR ----------
// kt[nt*512 + ks*64 + r*2 + hh] = f16(addr[nt*32 + r][16ks + 8hh .. +8])
// -> pass1's per-(tile,ks) A-frag load is 64 consecutive b128 = 1KB coalesced.
__global__ __launch_bounds__(512)
void prep_k(const float* __restrict__ addr, _Float16* __restrict__ kt)
{
  const int nt = blockIdx.x, ts = threadIdx.x;
  const int ks = ts >> 6, r = (ts >> 1) & 31, hh = ts & 1;
  const float* s = addr + (size_t)(nt*NT + r)*DDIM + 16*ks + 8*hh;
  float4 a = *(const float4*)s;
  float4 b = *(const float4*)(s + 4);
  union { f16x8 v; fp16v2 h[4]; } u;
  u.h[0] = __builtin_amdgcn_cvt_pkrtz(a.x, a.y);
  u.h[1] = __builtin_amdgcn_cvt_pkrtz(a.z, a.w);
  u.h[2] = __builtin_amdgcn_cvt_pkrtz(b.x, b.y);
  u.h[3] = __builtin_amdgcn_cvt_pkrtz(b.z, b.w);
  ((f16x8*)kt)[(size_t)nt*512 + ts] = u.v;
}

// ---------- prep 2: bank f32 [4096][512] -> V B-frag tiles bf16 (unchanged) --
__global__ __launch_bounds__(1024)
void prep_v(const float* __restrict__ bank, short* __restrict__ vt)
{
  const int nt = blockIdx.x, t = threadIdx.x;
  const int vv = t & 511, half = t >> 9;
  const float* src = bank + (size_t)(nt*NT + half*16) * VDIM + vv;
  float v[16];
  #pragma unroll
  for (int k = 0; k < 16; ++k) v[k] = src[(size_t)k * VDIM];
  uint4 p0, p1;
  p0.x = pkhi(v[1],  v[0]);  p0.y = pkhi(v[3],  v[2]);
  p0.z = pkhi(v[5],  v[4]);  p0.w = pkhi(v[7],  v[6]);
  p1.x = pkhi(v[9],  v[8]);  p1.y = pkhi(v[11], v[10]);
  p1.z = pkhi(v[13], v[12]); p1.w = pkhi(v[15], v[14]);
  uint4* dst = (uint4*)vt + ((size_t)nt*1024 + t)*2;
  dst[0] = p0; dst[1] = p1;
}

// ---------- pass 1: S = Q.K^T, exp2, P A-frags + den partials --------------
// NO LDS, NO BARRIERS: waves free-run. A-frags loaded lane-direct from the
// frag-major kt (1KB coalesced, L2-resident). Numerics/layout byte-identical
// to the round-8 verified path (dual S chains, exp2, pkhi, permlane pack).
__global__ __launch_bounds__(256, 4)
void pass1_kernel(const float* __restrict__ sel,
                  const _Float16* __restrict__ kt,
                  short* __restrict__ pt,       // chunk-local P frags
                  float* __restrict__ den,      // [MTOT][8] partials
                  int m_off)
{
  const int tid  = threadIdx.x;
  const int wave = tid >> 6;
  const int lane = tid & 63;
  const int h    = lane >> 5;
  const int c32  = lane & 31;

  const int nq  = blockIdx.x & 7;
  const int mbl = blockIdx.x >> 3;
  const int m0  = m_off + mbl * 128;
  const int wm  = wave * 32;
  const int mtl = mbl * 4 + wave;

  // Q fragments (B operand: col m = c32, rows d = 16ks+8h+e), log2e-scaled
  f16x8 aQ[8];
  {
    const float* q = sel + (size_t)(m0 + wm + c32) * DDIM + 8*h;
    #pragma unroll
    for (int ks = 0; ks < 8; ++ks){
      float4 a = *(const float4*)(q + 16*ks);
      float4 b = *(const float4*)(q + 16*ks + 4);
      f16x8 f;
      f[0]=(_Float16)(a.x*LOG2E); f[1]=(_Float16)(a.y*LOG2E);
      f[2]=(_Float16)(a.z*LOG2E); f[3]=(_Float16)(a.w*LOG2E);
      f[4]=(_Float16)(b.x*LOG2E); f[5]=(_Float16)(b.y*LOG2E);
      f[6]=(_Float16)(b.z*LOG2E); f[7]=(_Float16)(b.w*LOG2E);
      aQ[ks] = f;
    }
  }

  f32x16 zc;
  #pragma unroll
  for (int r=0;r<16;++r) zc[r] = 0.f;
  asm volatile("" : "+v"(zc));

  float lacc = 0.f;

  const f16x8* kb = (const f16x8*)kt + (size_t)(nq*16)*512;
  bf16x8* pbase = (bf16x8*)pt + (size_t)mtl * NTILES * 128;
  const int fl = c32*2 + h;          // frag-lane offset within a 64-frag group

  for (int t = 0; t < 16; ++t){
    // A-frags for this n-tile: 8 coalesced b128 loads (L2-hot)
    f16x8 aK[8];
    #pragma unroll
    for (int ks=0;ks<8;++ks)
      aK[ks] = kb[(size_t)t*512 + ks*64 + fl];

    // S^T = K.Q^T : two independent 4-chains (verified numerics)
    __builtin_amdgcn_s_setprio(1);
    f32x16 sAcc0, sAcc1;
    sAcc0 = __builtin_amdgcn_mfma_f32_32x32x16_f16(aK[0], aQ[0], zc, 0,0,0);
    sAcc1 = __builtin_amdgcn_mfma_f32_32x32x16_f16(aK[1], aQ[1], zc, 0,0,0);
    #pragma unroll
    for (int ks=1; ks<4; ++ks){
      sAcc0 = __builtin_amdgcn_mfma_f32_32x32x16_f16(aK[2*ks],   aQ[2*ks],   sAcc0, 0,0,0);
      sAcc1 = __builtin_amdgcn_mfma_f32_32x32x16_f16(aK[2*ks+1], aQ[2*ks+1], sAcc1, 0,0,0);
    }
    __builtin_amdgcn_s_setprio(0);

    // P = 2^S, bf16-trunc; den partial accumulates the truncated values
    unsigned dw[2][4];
    #pragma unroll
    for (int j=0;j<2;++j)
      #pragma unroll
      for (int i=0;i<4;++i){
        float pa = __builtin_amdgcn_exp2f(sAcc0[8*j + 2*i]     + sAcc1[8*j + 2*i]);
        float pb = __builtin_amdgcn_exp2f(sAcc0[8*j + 2*i + 1] + sAcc1[8*j + 2*i + 1]);
        lacc += __uint_as_float(__float_as_uint(pa) & 0xffff0000u);
        lacc += __uint_as_float(__float_as_uint(pb) & 0xffff0000u);
        dw[j][i] = pkhi(pb, pa);
      }

    // pack to A-frags (verified permlane path), store (coalesced 2KB/wave)
    const int nt = nq*16 + t;
    #pragma unroll
    for (int j=0;j<2;++j){
      auto s02 = __builtin_amdgcn_permlane32_swap(dw[j][0], dw[j][2], false, false);
      auto s13 = __builtin_amdgcn_permlane32_swap(dw[j][1], dw[j][3], false, false);
      union { unsigned u[4]; bf16x8 v; } ap;
      ap.u[0] = s02[0]; ap.u[1] = s13[0]; ap.u[2] = s02[1]; ap.u[3] = s13[1];
      pbase[((size_t)nt*64 + lane)*2 + j] = ap.v;
    }
  }

  // den partial: lane holds rows m = c32 (half-waves cover n-halves)
  float tot = lacc + __shfl_xor(lacc, 32);
  if (lane < 32)
    den[(size_t)(m0 + wm + c32)*8 + nq] = tot;
}

// ---------- pass 2: O = P.V — streaming GEMM, P read ONCE ------------------
// Block: 8 waves (512 thr) own ONE m-tile (32 m) x all 512 v. All waves read
// the SAME A-frags (one HBM fetch, L1 broadcast); wave w covers v0 = w*64.
// No LDS, no barriers. 1-deep named-register prefetch. ~80 VGPR.
__global__ __launch_bounds__(512, 2)
void pass2_kernel(const short* __restrict__ pt,
                  const short* __restrict__ vt,
                  const float* __restrict__ den,
                  float* __restrict__ out,
                  int m_off)
{
  const int tid  = threadIdx.x;
  const int wave = tid >> 6;
  const int lane = tid & 63;
  const int h    = lane >> 5;
  const int c32  = lane & 31;

  const int mtl = blockIdx.x;             // chunk-local m-tile
  const int v0  = wave * 64;
  const int mg  = m_off + mtl * 32;

  const bf16x8* pa = (const bf16x8*)pt + (size_t)mtl * NTILES * 128;
  const bf16x8* vb = (const bf16x8*)vt;

  f32x16 oAcc[2];
  #pragma unroll
  for (int jv=0;jv<2;++jv)
    #pragma unroll
    for (int r=0;r<16;++r) oAcc[jv][r] = 0.f;

  bf16x8 A0a, A1a, B00a, B01a, B10a, B11a;
  bf16x8 A0b, A1b, B00b, B01b, B10b, B11b;

#define P2L(NTI, A0, A1, B00, B01, B10, B11)                              \
  { const size_t o = (size_t)(NTI);                                       \
    A0  = pa[(o*64 + lane)*2];                                            \
    A1  = pa[(o*64 + lane)*2 + 1];                                        \
    B00 = vb[o*2048 + (size_t)(      v0      + c32)*2 + h];               \
    B01 = vb[o*2048 + (size_t)(      v0 + 32 + c32)*2 + h];               \
    B10 = vb[o*2048 + (size_t)(512 + v0      + c32)*2 + h];               \
    B11 = vb[o*2048 + (size_t)(512 + v0 + 32 + c32)*2 + h]; }

#define P2M(A0, A1, B00, B01, B10, B11)                                   \
  { oAcc[0] = __builtin_amdgcn_mfma_f32_32x32x16_bf16(A0, B00, oAcc[0], 0,0,0); \
    oAcc[1] = __builtin_amdgcn_mfma_f32_32x32x16_bf16(A0, B01, oAcc[1], 0,0,0); \
    oAcc[0] = __builtin_amdgcn_mfma_f32_32x32x16_bf16(A1, B10, oAcc[0], 0,0,0); \
    oAcc[1] = __builtin_amdgcn_mfma_f32_32x32x16_bf16(A1, B11, oAcc[1], 0,0,0); }

  P2L(0, A0a, A1a, B00a, B01a, B10a, B11a);
  for (int nt = 0; nt < NTILES; nt += 2){
    P2L(nt+1, A0b, A1b, B00b, B01b, B10b, B11b);
    P2M(A0a, A1a, B00a, B01a, B10a, B11a);
    if (nt + 2 < NTILES) P2L(nt+2, A0a, A1a, B00a, B01a, B10a, B11a);
    P2M(A0b, A1b, B00b, B01b, B10b, B11b);
  }
#undef P2L
#undef P2M

  // epilogue: den = sum of 8 partials; divide + store
  #pragma unroll
  for (int r=0;r<16;++r){
    const int mrow = (r&3) + 8*(r>>2) + 4*h;
    const int m = mg + mrow;
    float4 d0 = *(const float4*)&den[(size_t)m*8];
    float4 d1 = *(const float4*)&den[(size_t)m*8 + 4];
    const float inv = 1.0f / (d0.x+d0.y+d0.z+d0.w + d1.x+d1.y+d1.z+d1.w);
    float* op = out + (size_t)m * VDIM + v0 + c32;
    op[0]  = oAcc[0][r] * inv;
    op[32] = oAcc[1][r] * inv;
  }
}

extern "C" void kernel_launch(void* const* d_in, const int* in_sizes, int n_in,
                              void* d_out, int out_size, void* d_ws, size_t ws_size,
                              hipStream_t stream) {
  const float* sel  = (const float*)d_in[0];   // [8,2048,128]
  const float* bank = (const float*)d_in[1];   // [4096,512]
  const float* addr = (const float*)d_in[2];   // [4096,128]
  float* out = (float*)d_out;                  // [8,2048,512]

  char* ws = (char*)d_ws;
  _Float16* kt  = (_Float16*)ws;                 // 1 MB   frag-major f16 K
  short*    vt  = (short*)(ws + (1u<<20));       // 4 MB   bf16 V B-frags
  float*    den = (float*)(ws + (5u<<20));       // 512 KB den partials [m][8]
  short*    pt  = (short*)(ws + (6u<<20));       // P frags (chunked)

  // adaptive m-chunking so P fits the workspace (full = 134 MB)
  int CM = MTOT;
  while (CM > 2048 && (size_t)(6u<<20) + (size_t)CM*NADDR*2 > ws_size) CM >>= 1;

  hipLaunchKernelGGL(prep_k, dim3(NTILES), dim3(512),  0, stream, addr, kt);
  hipLaunchKernelGGL(prep_v, dim3(NTILES), dim3(1024), 0, stream, bank, vt);
  for (int mo = 0; mo < MTOT; mo += CM){
    hipLaunchKernelGGL(pass1_kernel, dim3(CM/16), dim3(256), 0, stream,
                       sel, kt, pt, den, mo);
    hipLaunchKernelGGL(pass2_kernel, dim3(CM/32), dim3(512), 0, stream,
                       pt, vt, den, out, mo);
  }
}

// Round 10
// 204.200 us; speedup vs baseline: 1.1484x; 1.1484x over previous
//
#include <hip/hip_runtime.h>

typedef __attribute__((ext_vector_type(8))) short bf16x8;
typedef __attribute__((ext_vector_type(8))) _Float16 f16x8;
typedef __attribute__((ext_vector_type(2))) __fp16 fp16v2;
typedef __attribute__((ext_vector_type(16))) float f32x16;

#define DDIM 128
#define NADDR 4096
#define VDIM 512
#define MTOT 16384
#define NT 32
#define NTILES (NADDR/NT)      // 128 n-tiles
#define LOG2E 1.44269504088896340736f

// pack bf16-trunc(lo) into low short, bf16-trunc(hi) into high short
__device__ __forceinline__ unsigned pkhi(float hi, float lo){
  return __builtin_amdgcn_perm(__float_as_uint(hi), __float_as_uint(lo), 0x07060302u);
}

// async global->LDS, 16B per lane, dest = uniform base + lane*16
#define GLD_LDS(GSRC, LDST)                                                     \
  __builtin_amdgcn_global_load_lds(                                             \
      (const __attribute__((address_space(1))) unsigned*)(GSRC),                \
      (__attribute__((address_space(3))) unsigned*)(LDST), 16, 0, 0)

// ---------- prep 1: addr f32 [4096][128] -> K tiles f16, FRAG-MAJOR ----------
__global__ __launch_bounds__(512)
void prep_k(const float* __restrict__ addr, _Float16* __restrict__ kt)
{
  const int nt = blockIdx.x, ts = threadIdx.x;
  const int ks = ts >> 6, r = (ts >> 1) & 31, hh = ts & 1;
  const float* s = addr + (size_t)(nt*NT + r)*DDIM + 16*ks + 8*hh;
  float4 a = *(const float4*)s;
  float4 b = *(const float4*)(s + 4);
  union { f16x8 v; fp16v2 h[4]; } u;
  u.h[0] = __builtin_amdgcn_cvt_pkrtz(a.x, a.y);
  u.h[1] = __builtin_amdgcn_cvt_pkrtz(a.z, a.w);
  u.h[2] = __builtin_amdgcn_cvt_pkrtz(b.x, b.y);
  u.h[3] = __builtin_amdgcn_cvt_pkrtz(b.z, b.w);
  ((f16x8*)kt)[(size_t)nt*512 + ts] = u.v;
}

// ---------- prep 2: bank f32 [4096][512] -> V B-frag tiles bf16 --------------
__global__ __launch_bounds__(1024)
void prep_v(const float* __restrict__ bank, short* __restrict__ vt)
{
  const int nt = blockIdx.x, t = threadIdx.x;
  const int vv = t & 511, half = t >> 9;
  const float* src = bank + (size_t)(nt*NT + half*16) * VDIM + vv;
  float v[16];
  #pragma unroll
  for (int k = 0; k < 16; ++k) v[k] = src[(size_t)k * VDIM];
  uint4 p0, p1;
  p0.x = pkhi(v[1],  v[0]);  p0.y = pkhi(v[3],  v[2]);
  p0.z = pkhi(v[5],  v[4]);  p0.w = pkhi(v[7],  v[6]);
  p1.x = pkhi(v[9],  v[8]);  p1.y = pkhi(v[11], v[10]);
  p1.z = pkhi(v[13], v[12]); p1.w = pkhi(v[15], v[14]);
  uint4* dst = (uint4*)vt + ((size_t)nt*1024 + t)*2;
  dst[0] = p0; dst[1] = p1;
}

// ---------- pass 1: S = Q.K^T, exp2, P A-frags + den partials ---------------
// No LDS, no barriers (round-9 verified numerics). launch_bounds(256,3):
// the previous (256,4) forced a 128-VGPR cap on ~140 live regs -> spill risk.
__global__ __launch_bounds__(256, 3)
void pass1_kernel(const float* __restrict__ sel,
                  const _Float16* __restrict__ kt,
                  short* __restrict__ pt,
                  float* __restrict__ den,
                  int m_off)
{
  const int tid  = threadIdx.x;
  const int wave = tid >> 6;
  const int lane = tid & 63;
  const int h    = lane >> 5;
  const int c32  = lane & 31;

  const int nq  = blockIdx.x & 7;
  const int mbl = blockIdx.x >> 3;
  const int m0  = m_off + mbl * 128;
  const int wm  = wave * 32;
  const int mtl = mbl * 4 + wave;

  f16x8 aQ[8];
  {
    const float* q = sel + (size_t)(m0 + wm + c32) * DDIM + 8*h;
    #pragma unroll
    for (int ks = 0; ks < 8; ++ks){
      float4 a = *(const float4*)(q + 16*ks);
      float4 b = *(const float4*)(q + 16*ks + 4);
      f16x8 f;
      f[0]=(_Float16)(a.x*LOG2E); f[1]=(_Float16)(a.y*LOG2E);
      f[2]=(_Float16)(a.z*LOG2E); f[3]=(_Float16)(a.w*LOG2E);
      f[4]=(_Float16)(b.x*LOG2E); f[5]=(_Float16)(b.y*LOG2E);
      f[6]=(_Float16)(b.z*LOG2E); f[7]=(_Float16)(b.w*LOG2E);
      aQ[ks] = f;
    }
  }

  f32x16 zc;
  #pragma unroll
  for (int r=0;r<16;++r) zc[r] = 0.f;
  asm volatile("" : "+v"(zc));

  float lacc = 0.f;

  const f16x8* kb = (const f16x8*)kt + (size_t)(nq*16)*512;
  bf16x8* pbase = (bf16x8*)pt + (size_t)mtl * NTILES * 128;
  const int fl = c32*2 + h;

  for (int t = 0; t < 16; ++t){
    f16x8 aK[8];
    #pragma unroll
    for (int ks=0;ks<8;++ks)
      aK[ks] = kb[(size_t)t*512 + ks*64 + fl];

    __builtin_amdgcn_s_setprio(1);
    f32x16 sAcc0, sAcc1;
    sAcc0 = __builtin_amdgcn_mfma_f32_32x32x16_f16(aK[0], aQ[0], zc, 0,0,0);
    sAcc1 = __builtin_amdgcn_mfma_f32_32x32x16_f16(aK[1], aQ[1], zc, 0,0,0);
    #pragma unroll
    for (int ks=1; ks<4; ++ks){
      sAcc0 = __builtin_amdgcn_mfma_f32_32x32x16_f16(aK[2*ks],   aQ[2*ks],   sAcc0, 0,0,0);
      sAcc1 = __builtin_amdgcn_mfma_f32_32x32x16_f16(aK[2*ks+1], aQ[2*ks+1], sAcc1, 0,0,0);
    }
    __builtin_amdgcn_s_setprio(0);

    unsigned dw[2][4];
    #pragma unroll
    for (int j=0;j<2;++j)
      #pragma unroll
      for (int i=0;i<4;++i){
        float pa = __builtin_amdgcn_exp2f(sAcc0[8*j + 2*i]     + sAcc1[8*j + 2*i]);
        float pb = __builtin_amdgcn_exp2f(sAcc0[8*j + 2*i + 1] + sAcc1[8*j + 2*i + 1]);
        lacc += __uint_as_float(__float_as_uint(pa) & 0xffff0000u);
        lacc += __uint_as_float(__float_as_uint(pb) & 0xffff0000u);
        dw[j][i] = pkhi(pb, pa);
      }

    const int nt = nq*16 + t;
    #pragma unroll
    for (int j=0;j<2;++j){
      auto s02 = __builtin_amdgcn_permlane32_swap(dw[j][0], dw[j][2], false, false);
      auto s13 = __builtin_amdgcn_permlane32_swap(dw[j][1], dw[j][3], false, false);
      union { unsigned u[4]; bf16x8 v; } ap;
      ap.u[0] = s02[0]; ap.u[1] = s13[0]; ap.u[2] = s02[1]; ap.u[3] = s13[1];
      pbase[((size_t)nt*64 + lane)*2 + j] = ap.v;
    }
  }

  float tot = lacc + __shfl_xor(lacc, 32);
  if (lane < 32)
    den[(size_t)(m0 + wm + c32)*8 + nq] = tot;
}

// ---------- pass 2: O = P.V — A via global_load_lds ring, NO barriers -------
// Block: 512 thr, 8 waves, 64 m (2 m-tiles) x 512 v; wave: 2mt x 64v.
// A(P): wave-PRIVATE 4-slot LDS ring, 4 gload_lds/tile, 3 tiles ahead ->
//   ~20 loads in flight per thread (not VGPR-capped) -> HBM-saturating.
// B(V): 2-deep register ring (L2-resident, ~300cy < 2-tile cover).
// vmcnt(20) before ds_read: after A(p)'s 4-load batch exactly
//   A(p+1..3)=12 + B(p),B(p+1)=8 can be outstanding (B(p-1) drained by
//   MFMA(p-1)'s compiler wait). Ring WAR safe: slot (p+3)&3 was read at
//   iter p-1, reads complete (lgkmcnt) before MFMA(p-1) < this issue.
__global__ __launch_bounds__(512)
void pass2_kernel(const short* __restrict__ pt,
                  const short* __restrict__ vt,
                  const float* __restrict__ den,
                  float* __restrict__ out,
                  int m_off)
{
  __shared__ __align__(16) short sA[8][4][2048];   // [wave][slot][4 frags x 512 shorts]

  const int tid  = threadIdx.x;
  const int wave = tid >> 6;
  const int lane = tid & 63;
  const int h    = lane >> 5;
  const int c32  = lane & 31;
  const int v0   = wave * 64;

  const int mtl0 = blockIdx.x * 2;        // chunk-local m-tile pair
  const int mg   = m_off + mtl0 * 32;

  const char* pA0 = (const char*)pt + (size_t)mtl0 * NTILES * 2048 + (size_t)lane*32;
  const char* pA1 = pA0 + (size_t)NTILES * 2048;
  const bf16x8* vb = (const bf16x8*)vt;

  short* sw = &sA[wave][0][0];            // wave-private base

  f32x16 oAcc[2][2];
  #pragma unroll
  for (int mt=0;mt<2;++mt)
    #pragma unroll
    for (int vg=0;vg<2;++vg)
      #pragma unroll
      for (int r=0;r<16;++r) oAcc[mt][vg][r] = 0.f;

  bf16x8 Br[2][4];   // [ring][vg + 2*j]

#define ISSUE_A(TL, SL) {                                                     \
    const size_t tb = (size_t)(TL)*2048;                                      \
    GLD_LDS(pA0 + tb,      sw + (SL)*2048);                                   \
    GLD_LDS(pA0 + tb + 16, sw + (SL)*2048 + 512);                             \
    GLD_LDS(pA1 + tb,      sw + (SL)*2048 + 1024);                            \
    GLD_LDS(pA1 + tb + 16, sw + (SL)*2048 + 1536); }

#define LOAD_B(TL, RI) { const size_t o2 = (size_t)(TL)*2048;                 \
    Br[RI][0] = vb[o2 + (size_t)(      v0      + c32)*2 + h];                 \
    Br[RI][1] = vb[o2 + (size_t)(      v0 + 32 + c32)*2 + h];                 \
    Br[RI][2] = vb[o2 + (size_t)(512 + v0      + c32)*2 + h];                 \
    Br[RI][3] = vb[o2 + (size_t)(512 + v0 + 32 + c32)*2 + h]; }

  // prologue: A slots 0..2 <- tiles 0..2; B tiles 0,1
  ISSUE_A(0, 0); ISSUE_A(1, 1); ISSUE_A(2, 2);
  LOAD_B(0, 0);  LOAD_B(1, 1);

  for (int p = 0; p < NTILES; ++p){
    const int bi = p & 1;
    ISSUE_A((p+3) & (NTILES-1), (p+3) & 3);

    asm volatile("s_waitcnt vmcnt(20)" ::: "memory");

    bf16x8 aA[2][2];
    #pragma unroll
    for (int mt=0;mt<2;++mt)
      #pragma unroll
      for (int j=0;j<2;++j)
        aA[mt][j] = *(const bf16x8*)(sw + (size_t)(p&3)*2048 + (mt*2+j)*512 + lane*8);

    __builtin_amdgcn_s_setprio(1);
    #pragma unroll
    for (int mt=0;mt<2;++mt)
      #pragma unroll
      for (int vg=0;vg<2;++vg){
        oAcc[mt][vg] = __builtin_amdgcn_mfma_f32_32x32x16_bf16(aA[mt][0], Br[bi][vg],   oAcc[mt][vg], 0,0,0);
        oAcc[mt][vg] = __builtin_amdgcn_mfma_f32_32x32x16_bf16(aA[mt][1], Br[bi][2+vg], oAcc[mt][vg], 0,0,0);
      }
    __builtin_amdgcn_s_setprio(0);

    LOAD_B((p+2) & (NTILES-1), bi);   // after MFMA(p): anti-dep keeps order
  }
#undef ISSUE_A
#undef LOAD_B

  // epilogue: den = sum of 8 partials; divide + store
  #pragma unroll
  for (int mt=0;mt<2;++mt){
    const int mbase = mg + mt*32;
    #pragma unroll
    for (int r=0;r<16;++r){
      const int mrow = (r&3) + 8*(r>>2) + 4*h;
      const int m = mbase + mrow;
      float4 d0 = *(const float4*)&den[(size_t)m*8];
      float4 d1 = *(const float4*)&den[(size_t)m*8 + 4];
      const float inv = 1.0f / (d0.x+d0.y+d0.z+d0.w + d1.x+d1.y+d1.z+d1.w);
      float* op = out + (size_t)m * VDIM + v0 + c32;
      op[0]  = oAcc[mt][0][r] * inv;
      op[32] = oAcc[mt][1][r] * inv;
    }
  }
}

extern "C" void kernel_launch(void* const* d_in, const int* in_sizes, int n_in,
                              void* d_out, int out_size, void* d_ws, size_t ws_size,
                              hipStream_t stream) {
  const float* sel  = (const float*)d_in[0];   // [8,2048,128]
  const float* bank = (const float*)d_in[1];   // [4096,512]
  const float* addr = (const float*)d_in[2];   // [4096,128]
  float* out = (float*)d_out;                  // [8,2048,512]

  char* ws = (char*)d_ws;
  _Float16* kt  = (_Float16*)ws;                 // 1 MB   frag-major f16 K
  short*    vt  = (short*)(ws + (1u<<20));       // 4 MB   bf16 V B-frags
  float*    den = (float*)(ws + (5u<<20));       // 512 KB den partials [m][8]
  short*    pt  = (short*)(ws + (6u<<20));       // P frags (chunked)

  int CM = MTOT;
  while (CM > 2048 && (size_t)(6u<<20) + (size_t)CM*NADDR*2 > ws_size) CM >>= 1;

  hipLaunchKernelGGL(prep_k, dim3(NTILES), dim3(512),  0, stream, addr, kt);
  hipLaunchKernelGGL(prep_v, dim3(NTILES), dim3(1024), 0, stream, bank, vt);
  for (int mo = 0; mo < MTOT; mo += CM){
    hipLaunchKernelGGL(pass1_kernel, dim3(CM/16), dim3(256), 0, stream,
                       sel, kt, pt, den, mo);
    hipLaunchKernelGGL(pass2_kernel, dim3(CM/64), dim3(512), 0, stream,
                       pt, vt, den, out, mo);
  }
}

// Round 11
// 194.955 us; speedup vs baseline: 1.2029x; 1.0474x over previous
//
#include <hip/hip_runtime.h>

typedef __attribute__((ext_vector_type(8))) short bf16x8;
typedef __attribute__((ext_vector_type(8))) _Float16 f16x8;
typedef __attribute__((ext_vector_type(2))) __fp16 fp16v2;
typedef __attribute__((ext_vector_type(16))) float f32x16;

#define DDIM 128
#define NADDR 4096
#define VDIM 512
#define MTOT 16384
#define NT 32
#define NTILES (NADDR/NT)      // 128 n-tiles
#define LOG2E 1.44269504088896340736f

// pack bf16-trunc(lo) into low short, bf16-trunc(hi) into high short
__device__ __forceinline__ unsigned pkhi(float hi, float lo){
  return __builtin_amdgcn_perm(__float_as_uint(hi), __float_as_uint(lo), 0x07060302u);
}

// ---------- prep 1: addr f32 [4096][128] -> K tiles f16, FRAG-MAJOR ----------
__global__ __launch_bounds__(512)
void prep_k(const float* __restrict__ addr, _Float16* __restrict__ kt)
{
  const int nt = blockIdx.x, ts = threadIdx.x;
  const int ks = ts >> 6, r = (ts >> 1) & 31, hh = ts & 1;
  const float* s = addr + (size_t)(nt*NT + r)*DDIM + 16*ks + 8*hh;
  float4 a = *(const float4*)s;
  float4 b = *(const float4*)(s + 4);
  union { f16x8 v; fp16v2 h[4]; } u;
  u.h[0] = __builtin_amdgcn_cvt_pkrtz(a.x, a.y);
  u.h[1] = __builtin_amdgcn_cvt_pkrtz(a.z, a.w);
  u.h[2] = __builtin_amdgcn_cvt_pkrtz(b.x, b.y);
  u.h[3] = __builtin_amdgcn_cvt_pkrtz(b.z, b.w);
  ((f16x8*)kt)[(size_t)nt*512 + ts] = u.v;
}

// ---------- prep 2: bank f32 [4096][512] -> V B-frag tiles bf16 --------------
__global__ __launch_bounds__(1024)
void prep_v(const float* __restrict__ bank, short* __restrict__ vt)
{
  const int nt = blockIdx.x, t = threadIdx.x;
  const int vv = t & 511, half = t >> 9;
  const float* src = bank + (size_t)(nt*NT + half*16) * VDIM + vv;
  float v[16];
  #pragma unroll
  for (int k = 0; k < 16; ++k) v[k] = src[(size_t)k * VDIM];
  uint4 p0, p1;
  p0.x = pkhi(v[1],  v[0]);  p0.y = pkhi(v[3],  v[2]);
  p0.z = pkhi(v[5],  v[4]);  p0.w = pkhi(v[7],  v[6]);
  p1.x = pkhi(v[9],  v[8]);  p1.y = pkhi(v[11], v[10]);
  p1.z = pkhi(v[13], v[12]); p1.w = pkhi(v[15], v[14]);
  uint4* dst = (uint4*)vt + ((size_t)nt*1024 + t)*2;
  dst[0] = p0; dst[1] = p1;
}

// ---------- pass 1: S = Q.K^T, exp2, P A-frags + den partials ---------------
// Unchanged numerics (round-8..10 verified); ONLY the P-store layout changed
// to j-major (frag j contiguous 1KB) so pass2's staging is fully linear.
__global__ __launch_bounds__(256, 3)
void pass1_kernel(const float* __restrict__ sel,
                  const _Float16* __restrict__ kt,
                  short* __restrict__ pt,
                  float* __restrict__ den,
                  int m_off)
{
  const int tid  = threadIdx.x;
  const int wave = tid >> 6;
  const int lane = tid & 63;
  const int h    = lane >> 5;
  const int c32  = lane & 31;

  const int nq  = blockIdx.x & 7;
  const int mbl = blockIdx.x >> 3;
  const int m0  = m_off + mbl * 128;
  const int wm  = wave * 32;
  const int mtl = mbl * 4 + wave;

  f16x8 aQ[8];
  {
    const float* q = sel + (size_t)(m0 + wm + c32) * DDIM + 8*h;
    #pragma unroll
    for (int ks = 0; ks < 8; ++ks){
      float4 a = *(const float4*)(q + 16*ks);
      float4 b = *(const float4*)(q + 16*ks + 4);
      f16x8 f;
      f[0]=(_Float16)(a.x*LOG2E); f[1]=(_Float16)(a.y*LOG2E);
      f[2]=(_Float16)(a.z*LOG2E); f[3]=(_Float16)(a.w*LOG2E);
      f[4]=(_Float16)(b.x*LOG2E); f[5]=(_Float16)(b.y*LOG2E);
      f[6]=(_Float16)(b.z*LOG2E); f[7]=(_Float16)(b.w*LOG2E);
      aQ[ks] = f;
    }
  }

  f32x16 zc;
  #pragma unroll
  for (int r=0;r<16;++r) zc[r] = 0.f;
  asm volatile("" : "+v"(zc));

  float lacc = 0.f;

  const f16x8* kb = (const f16x8*)kt + (size_t)(nq*16)*512;
  bf16x8* pbase = (bf16x8*)pt + (size_t)mtl * NTILES * 128;
  const int fl = c32*2 + h;

  for (int t = 0; t < 16; ++t){
    f16x8 aK[8];
    #pragma unroll
    for (int ks=0;ks<8;++ks)
      aK[ks] = kb[(size_t)t*512 + ks*64 + fl];

    __builtin_amdgcn_s_setprio(1);
    f32x16 sAcc0, sAcc1;
    sAcc0 = __builtin_amdgcn_mfma_f32_32x32x16_f16(aK[0], aQ[0], zc, 0,0,0);
    sAcc1 = __builtin_amdgcn_mfma_f32_32x32x16_f16(aK[1], aQ[1], zc, 0,0,0);
    #pragma unroll
    for (int ks=1; ks<4; ++ks){
      sAcc0 = __builtin_amdgcn_mfma_f32_32x32x16_f16(aK[2*ks],   aQ[2*ks],   sAcc0, 0,0,0);
      sAcc1 = __builtin_amdgcn_mfma_f32_32x32x16_f16(aK[2*ks+1], aQ[2*ks+1], sAcc1, 0,0,0);
    }
    __builtin_amdgcn_s_setprio(0);

    unsigned dw[2][4];
    #pragma unroll
    for (int j=0;j<2;++j)
      #pragma unroll
      for (int i=0;i<4;++i){
        float pa = __builtin_amdgcn_exp2f(sAcc0[8*j + 2*i]     + sAcc1[8*j + 2*i]);
        float pb = __builtin_amdgcn_exp2f(sAcc0[8*j + 2*i + 1] + sAcc1[8*j + 2*i + 1]);
        lacc += __uint_as_float(__float_as_uint(pa) & 0xffff0000u);
        lacc += __uint_as_float(__float_as_uint(pb) & 0xffff0000u);
        dw[j][i] = pkhi(pb, pa);
      }

    const int nt = nq*16 + t;
    #pragma unroll
    for (int j=0;j<2;++j){
      auto s02 = __builtin_amdgcn_permlane32_swap(dw[j][0], dw[j][2], false, false);
      auto s13 = __builtin_amdgcn_permlane32_swap(dw[j][1], dw[j][3], false, false);
      union { unsigned u[4]; bf16x8 v; } ap;
      ap.u[0] = s02[0]; ap.u[1] = s13[0]; ap.u[2] = s02[1]; ap.u[3] = s13[1];
      pbase[(size_t)nt*128 + j*64 + lane] = ap.v;   // j-major: frag j = 1KB run
    }
  }

  float tot = lacc + __shfl_xor(lacc, 32);
  if (lane < 32)
    den[(size_t)(m0 + wm + c32)*8 + nq] = tot;
}

// ---------- pass 2: O = P.V — reg-relay LDS ring, raw barriers --------------
// Block 1024 thr / 16 waves: 64 m (2 m-tiles) x 512 v; wave = 2mt x 32v.
// NO vmem op writes LDS (no gload_lds) -> compiler never vmcnt-drains before
// ds_read. Staging: thread t owns 1 dword of each A-tile; loads tile p+4 to a
// reg (uniform queue across ALL waves -> tight uniform compiler vmcnt),
// ds_writes tile p+2 to a 4-slot ring (16KB LDS). Write->read separated by 2
// raw s_barriers; lgkmcnt(0) (not vmcnt!) published before each barrier.
__global__ __launch_bounds__(1024, 4)
void pass2_kernel(const short* __restrict__ pt,
                  const short* __restrict__ vt,
                  const float* __restrict__ den,
                  float* __restrict__ out,
                  int m_off)
{
  __shared__ __align__(16) short sA[4][2048];   // 4-slot ring, 4KB/slot

  const int tid  = threadIdx.x;
  const int wave = tid >> 6;
  const int lane = tid & 63;
  const int h    = lane >> 5;
  const int c32  = lane & 31;
  const int v0   = wave * 32;

  const int mtl0 = blockIdx.x * 2;
  const int mg   = m_off + mtl0 * 32;

  const bf16x8* vb = (const bf16x8*)vt;

  // staging map: thread owns tile-dword tid; frag f = tid>>8 = (mt<<1)|j
  const int f  = tid >> 8;
  const int lw = (tid >> 2) & 63;
  const int bw = (tid & 3) * 4;
  const char* psrc = (const char*)pt
      + (size_t)(mtl0 + (f >> 1)) * NTILES * 2048
      + (size_t)(f & 1) * 1024 + (size_t)lw * 16 + bw;
  unsigned* sdw = (unsigned*)&sA[0][0];

  f32x16 oAcc0, oAcc1;
  #pragma unroll
  for (int r=0;r<16;++r){ oAcc0[r] = 0.f; oAcc1[r] = 0.f; }

  bf16x8 BrA0, BrA1, BrB0, BrB1;
  unsigned dwA, dwB;

#define LOAD_B(TL, R0, R1) { const size_t o2 = (size_t)((TL)&(NTILES-1))*2048; \
    R0 = vb[o2 + (size_t)(      v0 + c32)*2 + h];                              \
    R1 = vb[o2 + (size_t)(512 + v0 + c32)*2 + h]; }

  // prologue: tiles 0,1 -> LDS; dwA/dwB = tiles 2,3; B tiles 0,1
  {
    unsigned d0 = *(const unsigned*)(psrc);
    unsigned d1 = *(const unsigned*)(psrc + 2048);
    dwA = *(const unsigned*)(psrc + 2*2048);
    dwB = *(const unsigned*)(psrc + 3*2048);
    LOAD_B(0, BrA0, BrA1);
    LOAD_B(1, BrB0, BrB1);
    sdw[tid] = d0;
    sdw[1024 + tid] = d1;
    __syncthreads();
  }

#define BODY(P, DW, B0, B1) {                                                  \
    sdw[((((P)+2)&3)<<10) + tid] = DW;              /* publish tile P+2 */     \
    const short* sb = &sA[0][0] + (((P)&3)<<11);                               \
    bf16x8 a0 = *(const bf16x8*)(sb +        lane*8);                          \
    bf16x8 a1 = *(const bf16x8*)(sb +  512 + lane*8);                          \
    bf16x8 a2 = *(const bf16x8*)(sb + 1024 + lane*8);                          \
    bf16x8 a3 = *(const bf16x8*)(sb + 1536 + lane*8);                          \
    __builtin_amdgcn_s_setprio(1);                                             \
    oAcc0 = __builtin_amdgcn_mfma_f32_32x32x16_bf16(a0, B0, oAcc0, 0,0,0);     \
    oAcc1 = __builtin_amdgcn_mfma_f32_32x32x16_bf16(a2, B0, oAcc1, 0,0,0);     \
    oAcc0 = __builtin_amdgcn_mfma_f32_32x32x16_bf16(a1, B1, oAcc0, 0,0,0);     \
    oAcc1 = __builtin_amdgcn_mfma_f32_32x32x16_bf16(a3, B1, oAcc1, 0,0,0);     \
    __builtin_amdgcn_s_setprio(0);                                             \
    LOAD_B((P)+2, B0, B1);                                                     \
    DW = *(const unsigned*)(psrc + (size_t)(((P)+4)&(NTILES-1))*2048);         \
    asm volatile("s_waitcnt lgkmcnt(0)" ::: "memory");                         \
    __builtin_amdgcn_s_barrier();                                              \
    asm volatile("" ::: "memory"); }

  for (int p = 0; p < NTILES; p += 2){
    BODY(p,   dwA, BrA0, BrA1);
    BODY(p+1, dwB, BrB0, BrB1);
  }
#undef BODY
#undef LOAD_B

  // epilogue: den = sum of 8 partials; divide + store
  #pragma unroll
  for (int mt=0; mt<2; ++mt){
    const f32x16& oa = mt ? oAcc1 : oAcc0;
    const int mbase = mg + mt*32;
    #pragma unroll
    for (int r=0;r<16;++r){
      const int mrow = (r&3) + 8*(r>>2) + 4*h;
      const int m = mbase + mrow;
      float4 d0 = *(const float4*)&den[(size_t)m*8];
      float4 d1 = *(const float4*)&den[(size_t)m*8 + 4];
      const float inv = 1.0f / (d0.x+d0.y+d0.z+d0.w + d1.x+d1.y+d1.z+d1.w);
      out[(size_t)m * VDIM + v0 + c32] = oa[r] * inv;
    }
  }
}

extern "C" void kernel_launch(void* const* d_in, const int* in_sizes, int n_in,
                              void* d_out, int out_size, void* d_ws, size_t ws_size,
                              hipStream_t stream) {
  const float* sel  = (const float*)d_in[0];   // [8,2048,128]
  const float* bank = (const float*)d_in[1];   // [4096,512]
  const float* addr = (const float*)d_in[2];   // [4096,128]
  float* out = (float*)d_out;                  // [8,2048,512]

  char* ws = (char*)d_ws;
  _Float16* kt  = (_Float16*)ws;                 // 1 MB   frag-major f16 K
  short*    vt  = (short*)(ws + (1u<<20));       // 4 MB   bf16 V B-frags
  float*    den = (float*)(ws + (5u<<20));       // 512 KB den partials [m][8]
  short*    pt  = (short*)(ws + (6u<<20));       // P frags (chunked)

  int CM = MTOT;
  while (CM > 2048 && (size_t)(6u<<20) + (size_t)CM*NADDR*2 > ws_size) CM >>= 1;

  hipLaunchKernelGGL(prep_k, dim3(NTILES), dim3(512),  0, stream, addr, kt);
  hipLaunchKernelGGL(prep_v, dim3(NTILES), dim3(1024), 0, stream, bank, vt);
  for (int mo = 0; mo < MTOT; mo += CM){
    hipLaunchKernelGGL(pass1_kernel, dim3(CM/16), dim3(256), 0, stream,
                       sel, kt, pt, den, mo);
    hipLaunchKernelGGL(pass2_kernel, dim3(CM/64), dim3(1024), 0, stream,
                       pt, vt, den, out, mo);
  }
}